// Round 14
// baseline (115.573 us; speedup 1.0000x reference)
//
#include <hip/hip_runtime.h>

// HMM forward, LINEAR domain, power-of-2 rescaling. B=64, D=128, A=128.
// R14 = R13 with LOAD-ALL-THEN-PROCESS staging in pairs & quads (MLP 8->64).
// R13 budget: fill 45 | pairs ~25 | quads ~10 | fwd 19 | overhead ~15.
// pairs/quads staging loops ran at MLP~8 (unroll-8 with dependent exp/DPP
// chain per iter) -> ~8 rounds of HBM/L3 latency per phase. Preloading ALL
// rows into registers first (pairs: 64 float2 = 128 VGPR; quads: 64 uints)
// collapses that to 1-2 rounds. No layout/numerics change; fwd untouched.
// Pipeline (validated R11/R13): pairs P_s^{(ab)} = Ê^a_{2s}·Ê^b_{2s+1} (x256,
// 253 blks) -> quads Q_S^{(abcd)} = P_{2S}^{(ab)}·P_{2S+1}^{(cd)}/256 (496
// blks) -> fwd 33 serial steps (31 quads + pair62 + single126), matrix by
// x-bits, L subtracts 33*8 bits (Eacc - 264).
// ws: mats 0..253 pairs+leftover, LP at 254*8192 uints, quads mats 256..751.

#define B_ 64
#define D_ 128
#define A_ 128

#define LP_OFF (254 * 8192)   // uint index; log_p_a1[j] fp32
#define QMAT 256              // quad mats start at mat index 256

typedef _Float16 h2 __attribute__((ext_vector_type(2)));
typedef _Float16 f16x8 __attribute__((ext_vector_type(8)));
typedef float f32x4 __attribute__((ext_vector_type(4)));

__device__ __forceinline__ unsigned packrtz(float a, float b) {
    auto p = __builtin_amdgcn_cvt_pkrtz(a, b); // low=a, high=b
    return __builtin_bit_cast(unsigned, p);
}
__device__ __forceinline__ float dot2acc(unsigned e, unsigned s, float acc) {
    return __builtin_amdgcn_fdot2(__builtin_bit_cast(h2, e),
                                  __builtin_bit_cast(h2, s), acc, false);
}
__device__ __forceinline__ unsigned pkmax(unsigned a, unsigned b) {
    unsigned d;
    asm("v_pk_max_f16 %0, %1, %2" : "=v"(d) : "v"(a), "v"(b));
    return d;
}
__device__ __forceinline__ unsigned pkmul(unsigned a, unsigned b) {
    unsigned d;
    asm("v_pk_mul_f16 %0, %1, %2" : "=v"(d) : "v"(a), "v"(b));
    return d;
}
__device__ __forceinline__ unsigned pkmax4(uint4 u) {
    return pkmax(pkmax(u.x, u.y), pkmax(u.z, u.w));
}

template <int CTRL>
__device__ __forceinline__ float dpp_mov_self(float x) {
    return __int_as_float(__builtin_amdgcn_update_dpp(
        __float_as_int(x), __float_as_int(x), CTRL, 0xF, 0xF, false));
}
template <int CTRL>
__device__ __forceinline__ float dpp_mov_zero(float x) {
    return __int_as_float(__builtin_amdgcn_update_dpp(
        0, __float_as_int(x), CTRL, 0xF, 0xF, true));
}
__device__ __forceinline__ float wave_max_bcast(float x) {
    x = fmaxf(x, dpp_mov_self<0x111>(x));
    x = fmaxf(x, dpp_mov_self<0x112>(x));
    x = fmaxf(x, dpp_mov_self<0x114>(x));
    x = fmaxf(x, dpp_mov_self<0x118>(x));
    x = fmaxf(x, dpp_mov_self<0x142>(x));
    x = fmaxf(x, dpp_mov_self<0x143>(x));
    return __int_as_float(__builtin_amdgcn_readlane(__float_as_int(x), 63));
}
__device__ __forceinline__ float wave_sum_bcast(float x) {
    x += dpp_mov_zero<0x111>(x);
    x += dpp_mov_zero<0x112>(x);
    x += dpp_mov_zero<0x114>(x);
    x += dpp_mov_zero<0x118>(x);
    x += dpp_mov_zero<0x142>(x);
    x += dpp_mov_zero<0x143>(x);
    return __int_as_float(__builtin_amdgcn_readlane(__float_as_int(x), 63));
}

__device__ __forceinline__ f32x4 mfma16(uint4 a, uint4 b, f32x4 c) {
    return __builtin_amdgcn_mfma_f32_16x16x32_f16(
        __builtin_bit_cast(f16x8, a), __builtin_bit_cast(f16x8, b), c, 0, 0, 0);
}

// ---------------- pairs kernel: 253 blocks x 256 ----------------
// block b<252: s = b>>2, a = (b>>1)&1, bsel = b&1 -> ONE product
//   P_s^{(a,bsel)} = Ê^a_{2s}·Ê^bsel_{2s+1} (x256), fwd layout.
// block 252:   leftover Ê^a_126 (x256) in fwd layout + LP + out[1]
// fwd layout (uints, per matrix 8192): addr = q*1024+h*512+w*128+jl*4+c
//   packs (P[2i][j], P[2i+1][j]), i = 32h+4q+c, j = 32w+jl.
__global__ __launch_bounds__(256, 1) void pairs(const float* __restrict__ uT,
                                                const float* __restrict__ u1,
                                                const float* __restrict__ x,
                                                const float* __restrict__ lg,
                                                float* __restrict__ ws,
                                                float* __restrict__ out) {
    const int blk = blockIdx.x, tid = threadIdx.x;
    const int wave = tid >> 6, lane = tid & 63;
    unsigned* P = (unsigned*)ws;

    if (blk == 252) {  // ---- leftover Ê_126, both combos, fwd layout ----
        __shared__ float Zl[A_], bcs[2][A_];
        const float* u = uT + (size_t)126 * A_ * A_;
        for (int rr = 0; rr < 32; rr += 4) {
#pragma unroll
            for (int qq = 0; qq < 4; qq++) {
                int r = wave * 32 + rr + qq;
                float2 uv = *(const float2*)&u[r * A_ + 2 * lane];
                float ss = wave_sum_bcast(__expf(uv.x) + __expf(uv.y));
                if (lane == 0) Zl[r] = __logf(ss);
            }
        }
        if (tid < A_) {
            float lv = lg[127 * A_ + tid];
            float sg = 1.f / (1.f + __expf(-lv));
            bcs[1][tid] = sg * 256.f;
            bcs[0][tid] = (1.f - sg) * 256.f;
        }
        __syncthreads();
        unsigned* E0o = P + (size_t)252 * 8192;
        unsigned* E1o = P + (size_t)253 * 8192;
#pragma unroll 4
        for (int it = 0; it < 32; it++) {
            int a = it * 256 + tid;
            int c = a & 3, jl = (a >> 2) & 31, w = (a >> 7) & 3;
            int h = (a >> 9) & 1, q = (a >> 10) & 7;
            int j = 32 * w + jl, i = 32 * h + 4 * q + c;
            float e0 = __expf(u[(2 * i) * A_ + j] - Zl[2 * i]);
            float e1 = __expf(u[(2 * i) * A_ + A_ + j] - Zl[2 * i + 1]);
            E0o[a] = packrtz(e0 * bcs[0][j], e1 * bcs[0][j]);
            E1o[a] = packrtz(e0 * bcs[1][j], e1 * bcs[1][j]);
        }
        if (wave == 0) {  // LP + second output
            float a = u1[lane], c = u1[lane + 64];
            float mx = wave_max_bcast(fmaxf(a, c));
            float ss = wave_sum_bcast(__expf(a - mx) + __expf(c - mx));
            float lse = mx + __logf(ss);
            ws[LP_OFF + lane] = a - lse;
            ws[LP_OFF + lane + 64] = c - lse;
            out[B_ * A_ + lane] = a - lse;
            out[B_ * A_ + lane + 64] = c - lse;
        }
        return;
    }

    // ---- one product: s, variant (a, bsel) ----
    const int s = blk >> 2, a = (blk >> 1) & 1, bsel = blk & 1;
    __shared__ __align__(16) _Float16 E0l[128][136]; // [k][m] (row-major)
    __shared__ __align__(16) _Float16 E1l[128][136]; // [j][m] (E1 transposed)
    __shared__ unsigned bcp0[2][64];   // bc_{2s}[m] packed pairs
    __shared__ float bc1v[2][A_];      // bc_{2s+1}[j]
    const float* u0 = uT + (size_t)(2 * s) * A_ * A_;
    const float* u1m = uT + (size_t)(2 * s + 1) * A_ * A_;

    if (tid < 64) {        // bc0 packed pairs (m-pairs)
        float la = lg[(2 * s + 1) * A_ + 2 * tid];
        float lb = lg[(2 * s + 1) * A_ + 2 * tid + 1];
        float sa = 1.f / (1.f + __expf(-la)), sb = 1.f / (1.f + __expf(-lb));
        bcp0[1][tid] = packrtz(sa, sb);
        bcp0[0][tid] = packrtz(1.f - sa, 1.f - sb);
    } else if (tid < 192) { // bc1 per j
        int j = tid - 64;
        float lv = lg[(2 * s + 2) * A_ + j];
        float sg = 1.f / (1.f + __expf(-lv));
        bc1v[1][j] = sg;
        bc1v[0][j] = 1.f - sg;
    }

    // FUSED Z+staging, one read of u. LOAD-ALL-FIRST: all 64 float2 rows of
    // both matrices issued before any processing (MLP 64 vs unroll-8's 8).
    // e = exp(u) * rcp(sum(exp(u))) == exp(u - logsum) to << fp16 rounding.
    {
        const int rbase = wave * 32;
        float2 uv0[32], uv1[32];
#pragma unroll
        for (int rr = 0; rr < 32; rr++)
            uv0[rr] = *(const float2*)&u0[(rbase + rr) * A_ + 2 * lane];
#pragma unroll
        for (int rr = 0; rr < 32; rr++)
            uv1[rr] = *(const float2*)&u1m[(rbase + rr) * A_ + 2 * lane];
        __builtin_amdgcn_sched_barrier(0); // loads pinned before processing
#pragma unroll
        for (int rr = 0; rr < 32; rr++) {   // E0 row-major [k][m]
            int r = rbase + rr;
            float e0 = __expf(uv0[rr].x), e1 = __expf(uv0[rr].y);
            float rs = __builtin_amdgcn_rcpf(wave_sum_bcast(e0 + e1));
            *(unsigned*)&E0l[r][2 * lane] = packrtz(e0 * rs, e1 * rs);
        }
#pragma unroll
        for (int rr = 0; rr < 32; rr++) {   // E1 transposed [j][m]
            int m = rbase + rr;
            float e0 = __expf(uv1[rr].x), e1 = __expf(uv1[rr].y);
            float rs = __builtin_amdgcn_rcpf(wave_sum_bcast(e0 + e1));
            E1l[2 * lane][m] = (_Float16)(e0 * rs);
            E1l[2 * lane + 1][m] = (_Float16)(e1 * rs);
        }
    }
    __syncthreads();

    const int lo16 = lane & 15, g = lane >> 4;
    unsigned* Pg = P + (size_t)(s * 4 + a * 2 + bsel) * 8192;

    uint4 Bf[32];   // B-frags cached: col j=16nq+lo16, m = 32kc+8g..+7
#pragma unroll
    for (int nq = 0; nq < 8; nq++)
#pragma unroll
        for (int kc = 0; kc < 4; kc++)
            Bf[nq * 4 + kc] =
                *(const uint4*)&E1l[16 * nq + lo16][32 * kc + 8 * g];

    float mulf[8];
#pragma unroll
    for (int nq = 0; nq < 8; nq++)
        mulf[nq] = bc1v[bsel][16 * nq + lo16] * 256.f;

#pragma unroll
    for (int mi = 0; mi < 2; mi++) {
        const int mq = 2 * wave + mi;   // wave w owns mq = 2w, 2w+1
        uint4 Af[4];  // A row k=16mq+lo16, m = 32kc+8g..+7, times bc0^a[m]
#pragma unroll
        for (int kc = 0; kc < 4; kc++) {
            uint4 av = *(const uint4*)&E0l[16 * mq + lo16][32 * kc + 8 * g];
            uint4 bp = *(const uint4*)&bcp0[a][16 * kc + 4 * g];
            av.x = pkmul(av.x, bp.x);
            av.y = pkmul(av.y, bp.y);
            av.z = pkmul(av.z, bp.z);
            av.w = pkmul(av.w, bp.w);
            Af[kc] = av;
        }
        f32x4 acc[8];
#pragma unroll
        for (int nq = 0; nq < 8; nq++) {
            acc[nq] = (f32x4){0.f, 0.f, 0.f, 0.f};
#pragma unroll
            for (int kc = 0; kc < 4; kc++)
                acc[nq] = mfma16(Af[kc], Bf[nq * 4 + kc], acc[nq]);
        }
#pragma unroll
        for (int nq = 0; nq < 8; nq++) {
            int j = 16 * nq + lo16;
            int jpart = (j >> 5) * 128 + (j & 31) * 4;
            float mf = mulf[nq];
            unsigned p0 = packrtz(acc[nq][0] * mf, acc[nq][1] * mf);
            unsigned p1 = packrtz(acc[nq][2] * mf, acc[nq][3] * mf);
            int i0 = 8 * mq + 2 * g;       // rows (2i0, 2i0+1)
            int i1 = i0 + 1;               // rows (2i1, 2i1+1)
            Pg[((i0 >> 2) & 7) * 1024 + (i0 >> 5) * 512 + jpart + (i0 & 3)] = p0;
            Pg[((i1 >> 2) & 7) * 1024 + (i1 >> 5) * 512 + jpart + (i1 & 3)] = p1;
        }
    }
}

// ---------------- quads kernel: 496 blocks x 256 ----------------
// block = S*16 + v, v = a*8+b*4+c*2+d:
//   Q = P_{2S}^{(a,b)} · P_{2S+1}^{(c,d)} / 256, stored in fwd layout at
//   mat QMAT+blk. LOAD-ALL-FIRST staging (64 uints in regs), then unpack:
//   A: row-pair split to Al[i][k]; B: stored uint -> Bl[j][2k..2k+1].
__global__ __launch_bounds__(256, 1) void quads(float* __restrict__ ws) {
    __shared__ __align__(16) _Float16 Al[128][136]; // [i][k]
    __shared__ __align__(16) _Float16 Bl[128][136]; // [j][k]
    const int blk = blockIdx.x, tid = threadIdx.x;
    const int wave = tid >> 6, lane = tid & 63;
    const int S = blk >> 4, v = blk & 15;
    unsigned* P = (unsigned*)ws;
    const unsigned* P1 = P + (size_t)((2 * S) * 4 + (v >> 2)) * 8192;
    const unsigned* P2 = P + (size_t)((2 * S + 1) * 4 + (v & 3)) * 8192;
    unsigned* Q = P + (size_t)(QMAT + blk) * 8192;

    {
        unsigned v1s[32], v2s[32];
#pragma unroll
        for (int it = 0; it < 32; it++) v1s[it] = P1[it * 256 + tid];
#pragma unroll
        for (int it = 0; it < 32; it++) v2s[it] = P2[it * 256 + tid];
        __builtin_amdgcn_sched_barrier(0); // loads pinned before unpack
#pragma unroll
        for (int it = 0; it < 32; it++) {
            int a = it * 256 + tid;
            int c = a & 3, jl = (a >> 2) & 31, w = (a >> 7) & 3;
            int h = (a >> 9) & 1, q = (a >> 10) & 7;
            int i = 32 * h + 4 * q + c, j = 32 * w + jl;
            h2 p = __builtin_bit_cast(h2, v1s[it]);
            Al[2 * i][j] = p[0];
            Al[2 * i + 1][j] = p[1];
            *(unsigned*)&Bl[j][2 * i] = v2s[it];
        }
    }
    __syncthreads();

    const int lo16 = lane & 15, g = lane >> 4;
    const float mf = 1.f / 256.f;

    uint4 Bf[32];
#pragma unroll
    for (int nq = 0; nq < 8; nq++)
#pragma unroll
        for (int kc = 0; kc < 4; kc++)
            Bf[nq * 4 + kc] =
                *(const uint4*)&Bl[16 * nq + lo16][32 * kc + 8 * g];

#pragma unroll
    for (int mi = 0; mi < 2; mi++) {
        const int mq = 2 * wave + mi;
        uint4 Af[4];
#pragma unroll
        for (int kc = 0; kc < 4; kc++)
            Af[kc] = *(const uint4*)&Al[16 * mq + lo16][32 * kc + 8 * g];
        f32x4 acc[8];
#pragma unroll
        for (int nq = 0; nq < 8; nq++) {
            acc[nq] = (f32x4){0.f, 0.f, 0.f, 0.f};
#pragma unroll
            for (int kc = 0; kc < 4; kc++)
                acc[nq] = mfma16(Af[kc], Bf[nq * 4 + kc], acc[nq]);
        }
#pragma unroll
        for (int nq = 0; nq < 8; nq++) {
            int j = 16 * nq + lo16;
            int jpart = (j >> 5) * 128 + (j & 31) * 4;
            unsigned p0 = packrtz(acc[nq][0] * mf, acc[nq][1] * mf);
            unsigned p1 = packrtz(acc[nq][2] * mf, acc[nq][3] * mf);
            int i0 = 8 * mq + 2 * g;
            int i1 = i0 + 1;
            Q[((i0 >> 2) & 7) * 1024 + (i0 >> 5) * 512 + jpart + (i0 & 3)] = p0;
            Q[((i1 >> 2) & 7) * 1024 + (i1 >> 5) * 512 + jpart + (i1 & 3)] = p1;
        }
    }
}

// ---------------- fwd: 64 blocks x 256 (4 waves), 33 steps ----------------
#define BARRIER() asm volatile("s_waitcnt lgkmcnt(0)\n\ts_barrier" ::: "memory")

#define XBIT(PP) ((PP) < 64 ? (unsigned)((xlo >> (PP)) & 1ull) \
                            : (unsigned)((xhi >> ((PP) - 64)) & 1ull))
// steps 0..30: quads (bits x[4S+1..4S+4]); 31: pair s=62; 32: single t=126
#define PIDX33(S)                                                          \
    ((S) < 31 ? QMAT + (S)*16 +                                            \
                    (int)((XBIT(4 * (S) + 1) << 3) |                       \
                          (XBIT(4 * (S) + 2) << 2) |                       \
                          (XBIT(4 * (S) + 3) << 1) | XBIT(4 * (S) + 4))    \
              : ((S) == 31 ? 62 * 4 + (int)((XBIT(125) << 1) | XBIT(126))  \
                           : 252 + (int)XBIT(127)))

#define STEP(T, EC, EP, DOPF)                                                 \
    {                                                                         \
        const int p = (T) & 1, np = p ^ 1;                                    \
        const uint4* ewp = (const uint4*)&ewl[p][0] + h * 8;                  \
        uint4 ew_[8];                                                         \
        _Pragma("unroll") for (int q = 0; q < 8; q++) ew_[q] = ewp[q];        \
        __builtin_amdgcn_sched_barrier(0); /* ds_reads issue first */         \
        if (DOPF) { /* prefetch step T+2 (x-selected matrix) */               \
            int pidx_ = PIDX33((T) + 2);                                      \
            const uint4* pf = (const uint4*)(Pb + (size_t)pidx_ * 32768);     \
            _Pragma("unroll") for (int q = 0; q < 8; q++) EP[q] = pf[q * 256];\
            __builtin_amdgcn_sched_barrier(0); /* pin loads here */           \
        }                                                                     \
        unsigned mA = pkmax(pkmax(pkmax4(ew_[0]), pkmax4(ew_[1])),            \
                            pkmax(pkmax4(ew_[2]), pkmax4(ew_[3])));           \
        unsigned mB = pkmax(pkmax(pkmax4(ew_[4]), pkmax4(ew_[5])),            \
                            pkmax(pkmax4(ew_[6]), pkmax4(ew_[7])));           \
        unsigned mm = pkmax(mA, mB);                                          \
        auto mr = __builtin_amdgcn_permlane32_swap(mm, mm, false, false);     \
        mm = pkmax(mr[0], mr[1]);                                             \
        mm = pkmax(mm, mm >> 16);                                             \
        unsigned e16 = (mm >> 10) & 31;                                       \
        float f = __uint_as_float((142u - e16) << 23); /* 2^(15-e16) */       \
        Eacc += (int)e16 - 15;                                                \
        float s0 = 0, s1 = 0, s2 = 0, s3 = 0;                                 \
        float r0 = 0, r1 = 0, r2 = 0, r3 = 0;                                 \
        _Pragma("unroll") for (int q = 0; q < 4; q++) {                       \
            s0 = dot2acc(EC[q].x, ew_[q].x, s0);                              \
            s1 = dot2acc(EC[q].y, ew_[q].y, s1);                              \
            s2 = dot2acc(EC[q].z, ew_[q].z, s2);                              \
            s3 = dot2acc(EC[q].w, ew_[q].w, s3);                              \
        }                                                                     \
        _Pragma("unroll") for (int q = 4; q < 8; q++) {                       \
            r0 = dot2acc(EC[q].x, ew_[q].x, r0);                              \
            r1 = dot2acc(EC[q].y, ew_[q].y, r1);                              \
            r2 = dot2acc(EC[q].z, ew_[q].z, r2);                              \
            r3 = dot2acc(EC[q].w, ew_[q].w, r3);                              \
        }                                                                     \
        float Sh = ((s0 + s1) + (s2 + s3)) + ((r0 + r1) + (r2 + r3));         \
        auto sr = __builtin_amdgcn_permlane32_swap(__float_as_uint(Sh),       \
                                                   __float_as_uint(Sh),       \
                                                   false, false);             \
        float Stot = __uint_as_float(sr[0]) + __uint_as_float(sr[1]);         \
        float pv = Stot * f;                                                  \
        v = pv;                                                               \
        ewl[np][j] = (_Float16)pv;                                            \
        BARRIER();                                                            \
    }

__global__ __launch_bounds__(256, 1) void fwd(const float* __restrict__ x,
                                              const float* __restrict__ lg,
                                              const float* __restrict__ ws,
                                              float* __restrict__ out) {
    __shared__ __align__(16) _Float16 ewl[2][A_];
    __shared__ float sums[4];
    const int b = blockIdx.x, tid = threadIdx.x;
    const int w = tid >> 6, lane = tid & 63;
    const int h = lane >> 5, jl = lane & 31;
    const int j = 32 * w + jl;

    const char* Pb = (const char*)ws + (size_t)h * 2048 + w * 512 + jl * 16;
    const float* LP = ws + LP_OFF;

    // x-bit masks (wave-uniform) for matrix selection
    unsigned long long xlo = __ballot(x[b * D_ + lane] != 0.f);
    unsigned long long xhi = __ballot(x[b * D_ + 64 + lane] != 0.f);

    // init v_0[j] = log_p_a1[j] + bern(x[b][0], j) (log domain, once)
    float ll = lg[j];
    float sp = (ll > 0.f) ? (ll + log1pf(__expf(-ll))) : log1pf(__expf(ll));
    float xv0 = x[b * D_];
    float vlog = LP[j] + ((xv0 != 0.f) ? (ll - sp) : (-sp));
    float mw = wave_max_bcast(vlog);
    sums[w] = mw;
    BARRIER();
    float Phi0 = fmaxf(fmaxf(sums[0], sums[1]), fmaxf(sums[2], sums[3]));
    float v = __expf(vlog - Phi0);
    ewl[0][j] = (_Float16)v;
    int Eacc = 0;

    uint4 E0[8], E1[8], E2[8];
    {   // preload steps 0,1 (E2 filled by step 0's prefetch)
        int i0 = PIDX33(0), i1 = PIDX33(1);
        const uint4* p0 = (const uint4*)(Pb + (size_t)i0 * 32768);
        const uint4* p1 = (const uint4*)(Pb + (size_t)i1 * 32768);
#pragma unroll
        for (int q = 0; q < 8; q++) { E0[q] = p0[q * 256]; E1[q] = p1[q * 256]; }
        __builtin_amdgcn_sched_barrier(0);
    }
    BARRIER();

    for (int t = 0; t < 30; t += 3) {  // steps 0..29
        STEP(t + 0, E0, E2, 1)
        STEP(t + 1, E1, E0, 1)
        STEP(t + 2, E2, E1, 1)
    }
    STEP(30, E0, E2, 1)  // pf 32 -> E2
    STEP(31, E1, E0, 0)
    STEP(32, E2, E1, 0)

    // final: L = Phi0 + ln2*(Eacc - 33 steps * 8 bits of matrix x256 scale)
    //             + log(sum_j v[j])
    float sw = wave_sum_bcast(v) * 0.5f;  // halves duplicate j
    sums[w] = sw;
    BARRIER();
    float tot = (sums[0] + sums[1]) + (sums[2] + sums[3]);
    float L = Phi0 + 0.69314718055994531f * (float)(Eacc - 264) + __logf(tot);
    if (tid < A_) out[b * A_ + tid] = L;
}

extern "C" void kernel_launch(void* const* d_in, const int* in_sizes, int n_in,
                              void* d_out, int out_size, void* d_ws, size_t ws_size,
                              hipStream_t stream) {
    const float* x = (const float*)d_in[0];    // [B,D]
    const float* u1 = (const float*)d_in[1];   // [1,1,1,A]
    const float* uT = (const float*)d_in[2];   // [D-1,A,A]
    const float* lg = (const float*)d_in[3];   // [1,D,1,A]
    float* ws = (float*)d_ws;                  // ~24.6 MB used
    float* out = (float*)d_out;

    pairs<<<dim3(253), dim3(256), 0, stream>>>(uT, u1, x, lg, ws, out);
    quads<<<dim3(496), dim3(256), 0, stream>>>(ws);
    fwd<<<dim3(B_), dim3(256), 0, stream>>>(x, lg, ws, out);
}

// Round 15
// 108.480 us; speedup vs baseline: 1.0654x; 1.0654x over previous
//
#include <hip/hip_runtime.h>

// HMM forward, LINEAR domain, power-of-2 rescaling. B=64, D=128, A=128.
// R15 = R13/R14 with pairs & quads at 512 THREADS (8 waves = 2 waves/SIMD).
// R14's load-all-first was NEUTRAL -> staging-issue MLP wasn't the sink.
// Budget (R10-calibrated): fill 45 | pairs ~29 | quads ~12 | fwd ~20 | ovh ~7.
// pairs/quads ran 1 block/CU x 4 waves = 1 wave/SIMD: every DPP-reduce
// chain, exp, LDS round-trip and scattered store fully latency-exposed.
// Fix: 8 waves/block -> each wave stages 16 rows (half the serial chain)
// and owns ONE M-tile (mq = wave); B-frags loaded inline (no 128-reg cache,
// keeps pressure ~100 so 2 waves/SIMD materializes and cross-wave TLP
// hides the chains). Numerics/layouts/scatter/PIDX33/fwd verbatim.
// Pipeline (validated): pairs P_s^{(ab)} = Ê^a_{2s}·Ê^b_{2s+1} (x256, 253
// blks) -> quads Q_S^{(abcd)} = P_{2S}^{(ab)}·P_{2S+1}^{(cd)}/256 (496 blks)
// -> fwd 33 serial steps (31 quads + pair62 + single126), matrix by x-bits,
// L subtracts 33*8 bits (Eacc - 264).
// ws: mats 0..253 pairs+leftover, LP at 254*8192 uints, quads mats 256..751.

#define B_ 64
#define D_ 128
#define A_ 128

#define LP_OFF (254 * 8192)   // uint index; log_p_a1[j] fp32
#define QMAT 256              // quad mats start at mat index 256

typedef _Float16 h2 __attribute__((ext_vector_type(2)));
typedef _Float16 f16x8 __attribute__((ext_vector_type(8)));
typedef float f32x4 __attribute__((ext_vector_type(4)));

__device__ __forceinline__ unsigned packrtz(float a, float b) {
    auto p = __builtin_amdgcn_cvt_pkrtz(a, b); // low=a, high=b
    return __builtin_bit_cast(unsigned, p);
}
__device__ __forceinline__ float dot2acc(unsigned e, unsigned s, float acc) {
    return __builtin_amdgcn_fdot2(__builtin_bit_cast(h2, e),
                                  __builtin_bit_cast(h2, s), acc, false);
}
__device__ __forceinline__ unsigned pkmax(unsigned a, unsigned b) {
    unsigned d;
    asm("v_pk_max_f16 %0, %1, %2" : "=v"(d) : "v"(a), "v"(b));
    return d;
}
__device__ __forceinline__ unsigned pkmul(unsigned a, unsigned b) {
    unsigned d;
    asm("v_pk_mul_f16 %0, %1, %2" : "=v"(d) : "v"(a), "v"(b));
    return d;
}
__device__ __forceinline__ unsigned pkmax4(uint4 u) {
    return pkmax(pkmax(u.x, u.y), pkmax(u.z, u.w));
}

template <int CTRL>
__device__ __forceinline__ float dpp_mov_self(float x) {
    return __int_as_float(__builtin_amdgcn_update_dpp(
        __float_as_int(x), __float_as_int(x), CTRL, 0xF, 0xF, false));
}
template <int CTRL>
__device__ __forceinline__ float dpp_mov_zero(float x) {
    return __int_as_float(__builtin_amdgcn_update_dpp(
        0, __float_as_int(x), CTRL, 0xF, 0xF, true));
}
__device__ __forceinline__ float wave_max_bcast(float x) {
    x = fmaxf(x, dpp_mov_self<0x111>(x));
    x = fmaxf(x, dpp_mov_self<0x112>(x));
    x = fmaxf(x, dpp_mov_self<0x114>(x));
    x = fmaxf(x, dpp_mov_self<0x118>(x));
    x = fmaxf(x, dpp_mov_self<0x142>(x));
    x = fmaxf(x, dpp_mov_self<0x143>(x));
    return __int_as_float(__builtin_amdgcn_readlane(__float_as_int(x), 63));
}
__device__ __forceinline__ float wave_sum_bcast(float x) {
    x += dpp_mov_zero<0x111>(x);
    x += dpp_mov_zero<0x112>(x);
    x += dpp_mov_zero<0x114>(x);
    x += dpp_mov_zero<0x118>(x);
    x += dpp_mov_zero<0x142>(x);
    x += dpp_mov_zero<0x143>(x);
    return __int_as_float(__builtin_amdgcn_readlane(__float_as_int(x), 63));
}

__device__ __forceinline__ f32x4 mfma16(uint4 a, uint4 b, f32x4 c) {
    return __builtin_amdgcn_mfma_f32_16x16x32_f16(
        __builtin_bit_cast(f16x8, a), __builtin_bit_cast(f16x8, b), c, 0, 0, 0);
}

// ---------------- pairs kernel: 253 blocks x 512 (8 waves) ----------------
// block b<252: s = b>>2, a = (b>>1)&1, bsel = b&1 -> ONE product
//   P_s^{(a,bsel)} = Ê^a_{2s}·Ê^bsel_{2s+1} (x256), fwd layout.
// block 252:   leftover Ê^a_126 (x256) in fwd layout + LP + out[1]
// fwd layout (uints, per matrix 8192): addr = q*1024+h*512+w*128+jl*4+c
//   packs (P[2i][j], P[2i+1][j]), i = 32h+4q+c, j = 32w+jl.
__global__ __launch_bounds__(512, 1) void pairs(const float* __restrict__ uT,
                                                const float* __restrict__ u1,
                                                const float* __restrict__ x,
                                                const float* __restrict__ lg,
                                                float* __restrict__ ws,
                                                float* __restrict__ out) {
    const int blk = blockIdx.x, tid = threadIdx.x;
    const int wave = tid >> 6, lane = tid & 63;   // wave 0..7
    unsigned* P = (unsigned*)ws;

    if (blk == 252) {  // ---- leftover Ê_126, both combos, fwd layout ----
        __shared__ float Zl[A_], bcs[2][A_];
        const float* u = uT + (size_t)126 * A_ * A_;
        for (int rr = 0; rr < 16; rr += 4) {      // 8 waves x 16 rows
#pragma unroll
            for (int qq = 0; qq < 4; qq++) {
                int r = wave * 16 + rr + qq;
                float2 uv = *(const float2*)&u[r * A_ + 2 * lane];
                float ss = wave_sum_bcast(__expf(uv.x) + __expf(uv.y));
                if (lane == 0) Zl[r] = __logf(ss);
            }
        }
        if (tid < A_) {
            float lv = lg[127 * A_ + tid];
            float sg = 1.f / (1.f + __expf(-lv));
            bcs[1][tid] = sg * 256.f;
            bcs[0][tid] = (1.f - sg) * 256.f;
        }
        __syncthreads();
        unsigned* E0o = P + (size_t)252 * 8192;
        unsigned* E1o = P + (size_t)253 * 8192;
#pragma unroll 4
        for (int it = 0; it < 16; it++) {         // 16 x 512 = 8192
            int a = it * 512 + tid;
            int c = a & 3, jl = (a >> 2) & 31, w = (a >> 7) & 3;
            int h = (a >> 9) & 1, q = (a >> 10) & 7;
            int j = 32 * w + jl, i = 32 * h + 4 * q + c;
            float e0 = __expf(u[(2 * i) * A_ + j] - Zl[2 * i]);
            float e1 = __expf(u[(2 * i) * A_ + A_ + j] - Zl[2 * i + 1]);
            E0o[a] = packrtz(e0 * bcs[0][j], e1 * bcs[0][j]);
            E1o[a] = packrtz(e0 * bcs[1][j], e1 * bcs[1][j]);
        }
        if (wave == 0) {  // LP + second output
            float a = u1[lane], c = u1[lane + 64];
            float mx = wave_max_bcast(fmaxf(a, c));
            float ss = wave_sum_bcast(__expf(a - mx) + __expf(c - mx));
            float lse = mx + __logf(ss);
            ws[LP_OFF + lane] = a - lse;
            ws[LP_OFF + lane + 64] = c - lse;
            out[B_ * A_ + lane] = a - lse;
            out[B_ * A_ + lane + 64] = c - lse;
        }
        return;
    }

    // ---- one product: s, variant (a, bsel) ----
    const int s = blk >> 2, a = (blk >> 1) & 1, bsel = blk & 1;
    __shared__ __align__(16) _Float16 E0l[128][136]; // [k][m] (row-major)
    __shared__ __align__(16) _Float16 E1l[128][136]; // [j][m] (E1 transposed)
    __shared__ unsigned bcp0[2][64];   // bc_{2s}[m] packed pairs
    __shared__ float bc1v[2][A_];      // bc_{2s+1}[j]
    const float* u0 = uT + (size_t)(2 * s) * A_ * A_;
    const float* u1m = uT + (size_t)(2 * s + 1) * A_ * A_;

    if (tid < 64) {        // bc0 packed pairs (m-pairs)
        float la = lg[(2 * s + 1) * A_ + 2 * tid];
        float lb = lg[(2 * s + 1) * A_ + 2 * tid + 1];
        float sa = 1.f / (1.f + __expf(-la)), sb = 1.f / (1.f + __expf(-lb));
        bcp0[1][tid] = packrtz(sa, sb);
        bcp0[0][tid] = packrtz(1.f - sa, 1.f - sb);
    } else if (tid < 192) { // bc1 per j
        int j = tid - 64;
        float lv = lg[(2 * s + 2) * A_ + j];
        float sg = 1.f / (1.f + __expf(-lv));
        bc1v[1][j] = sg;
        bc1v[0][j] = 1.f - sg;
    }

    // FUSED Z+staging, one read of u. 8 waves x 16 rows each per matrix.
    // e = exp(u) * rcp(sum(exp(u))) == exp(u - logsum) to << fp16 rounding.
    {
        const int rbase = wave * 16;
        float2 uv0[16], uv1[16];
#pragma unroll
        for (int rr = 0; rr < 16; rr++)
            uv0[rr] = *(const float2*)&u0[(rbase + rr) * A_ + 2 * lane];
#pragma unroll
        for (int rr = 0; rr < 16; rr++)
            uv1[rr] = *(const float2*)&u1m[(rbase + rr) * A_ + 2 * lane];
        __builtin_amdgcn_sched_barrier(0); // loads pinned before processing
#pragma unroll
        for (int rr = 0; rr < 16; rr++) {   // E0 row-major [k][m]
            int r = rbase + rr;
            float e0 = __expf(uv0[rr].x), e1 = __expf(uv0[rr].y);
            float rs = __builtin_amdgcn_rcpf(wave_sum_bcast(e0 + e1));
            *(unsigned*)&E0l[r][2 * lane] = packrtz(e0 * rs, e1 * rs);
        }
#pragma unroll
        for (int rr = 0; rr < 16; rr++) {   // E1 transposed [j][m]
            int m = rbase + rr;
            float e0 = __expf(uv1[rr].x), e1 = __expf(uv1[rr].y);
            float rs = __builtin_amdgcn_rcpf(wave_sum_bcast(e0 + e1));
            E1l[2 * lane][m] = (_Float16)(e0 * rs);
            E1l[2 * lane + 1][m] = (_Float16)(e1 * rs);
        }
    }
    __syncthreads();

    const int lo16 = lane & 15, g = lane >> 4;
    unsigned* Pg = P + (size_t)(s * 4 + a * 2 + bsel) * 8192;

    // wave w owns M-tile mq = w. Af cached (reused across nq); B-frags
    // loaded inline from LDS (each used once -> no 128-reg cache).
    const int mq = wave;
    uint4 Af[4];
#pragma unroll
    for (int kc = 0; kc < 4; kc++) {
        uint4 av = *(const uint4*)&E0l[16 * mq + lo16][32 * kc + 8 * g];
        uint4 bp = *(const uint4*)&bcp0[a][16 * kc + 4 * g];
        av.x = pkmul(av.x, bp.x);
        av.y = pkmul(av.y, bp.y);
        av.z = pkmul(av.z, bp.z);
        av.w = pkmul(av.w, bp.w);
        Af[kc] = av;
    }
    f32x4 acc[8];
#pragma unroll
    for (int nq = 0; nq < 8; nq++) {
        acc[nq] = (f32x4){0.f, 0.f, 0.f, 0.f};
#pragma unroll
        for (int kc = 0; kc < 4; kc++)
            acc[nq] = mfma16(
                Af[kc],
                *(const uint4*)&E1l[16 * nq + lo16][32 * kc + 8 * g],
                acc[nq]);
    }
#pragma unroll
    for (int nq = 0; nq < 8; nq++) {
        int j = 16 * nq + lo16;
        int jpart = (j >> 5) * 128 + (j & 31) * 4;
        float mf = bc1v[bsel][j] * 256.f;
        unsigned p0 = packrtz(acc[nq][0] * mf, acc[nq][1] * mf);
        unsigned p1 = packrtz(acc[nq][2] * mf, acc[nq][3] * mf);
        int i0 = 8 * mq + 2 * g;       // rows (2i0, 2i0+1)
        int i1 = i0 + 1;               // rows (2i1, 2i1+1)
        Pg[((i0 >> 2) & 7) * 1024 + (i0 >> 5) * 512 + jpart + (i0 & 3)] = p0;
        Pg[((i1 >> 2) & 7) * 1024 + (i1 >> 5) * 512 + jpart + (i1 & 3)] = p1;
    }
}

// ---------------- quads kernel: 496 blocks x 512 (8 waves) ----------------
// block = S*16 + v, v = a*8+b*4+c*2+d:
//   Q = P_{2S}^{(a,b)} · P_{2S+1}^{(c,d)} / 256, stored in fwd layout at
//   mat QMAT+blk. Staging unpack: A: row-pair split to Al[i][k]; B: stored
//   uint -> Bl[j][2k..2k+1]. Wave w owns M-tile mq = w.
__global__ __launch_bounds__(512, 1) void quads(float* __restrict__ ws) {
    __shared__ __align__(16) _Float16 Al[128][136]; // [i][k]
    __shared__ __align__(16) _Float16 Bl[128][136]; // [j][k]
    const int blk = blockIdx.x, tid = threadIdx.x;
    const int wave = tid >> 6, lane = tid & 63;
    const int S = blk >> 4, v = blk & 15;
    unsigned* P = (unsigned*)ws;
    const unsigned* P1 = P + (size_t)((2 * S) * 4 + (v >> 2)) * 8192;
    const unsigned* P2 = P + (size_t)((2 * S + 1) * 4 + (v & 3)) * 8192;
    unsigned* Q = P + (size_t)(QMAT + blk) * 8192;

    {
        unsigned v1s[16], v2s[16];
#pragma unroll
        for (int it = 0; it < 16; it++) v1s[it] = P1[it * 512 + tid];
#pragma unroll
        for (int it = 0; it < 16; it++) v2s[it] = P2[it * 512 + tid];
        __builtin_amdgcn_sched_barrier(0); // loads pinned before unpack
#pragma unroll
        for (int it = 0; it < 16; it++) {
            int a = it * 512 + tid;
            int c = a & 3, jl = (a >> 2) & 31, w = (a >> 7) & 3;
            int h = (a >> 9) & 1, q = (a >> 10) & 7;
            int i = 32 * h + 4 * q + c, j = 32 * w + jl;
            h2 p = __builtin_bit_cast(h2, v1s[it]);
            Al[2 * i][j] = p[0];
            Al[2 * i + 1][j] = p[1];
            *(unsigned*)&Bl[j][2 * i] = v2s[it];
        }
    }
    __syncthreads();

    const int lo16 = lane & 15, g = lane >> 4;
    const float mf = 1.f / 256.f;
    const int mq = wave;

    uint4 Af[4];
#pragma unroll
    for (int kc = 0; kc < 4; kc++)
        Af[kc] = *(const uint4*)&Al[16 * mq + lo16][32 * kc + 8 * g];
    f32x4 acc[8];
#pragma unroll
    for (int nq = 0; nq < 8; nq++) {
        acc[nq] = (f32x4){0.f, 0.f, 0.f, 0.f};
#pragma unroll
        for (int kc = 0; kc < 4; kc++)
            acc[nq] = mfma16(
                Af[kc],
                *(const uint4*)&Bl[16 * nq + lo16][32 * kc + 8 * g],
                acc[nq]);
    }
#pragma unroll
    for (int nq = 0; nq < 8; nq++) {
        int j = 16 * nq + lo16;
        int jpart = (j >> 5) * 128 + (j & 31) * 4;
        unsigned p0 = packrtz(acc[nq][0] * mf, acc[nq][1] * mf);
        unsigned p1 = packrtz(acc[nq][2] * mf, acc[nq][3] * mf);
        int i0 = 8 * mq + 2 * g;
        int i1 = i0 + 1;
        Q[((i0 >> 2) & 7) * 1024 + (i0 >> 5) * 512 + jpart + (i0 & 3)] = p0;
        Q[((i1 >> 2) & 7) * 1024 + (i1 >> 5) * 512 + jpart + (i1 & 3)] = p1;
    }
}

// ---------------- fwd: 64 blocks x 256 (4 waves), 33 steps ----------------
#define BARRIER() asm volatile("s_waitcnt lgkmcnt(0)\n\ts_barrier" ::: "memory")

#define XBIT(PP) ((PP) < 64 ? (unsigned)((xlo >> (PP)) & 1ull) \
                            : (unsigned)((xhi >> ((PP) - 64)) & 1ull))
// steps 0..30: quads (bits x[4S+1..4S+4]); 31: pair s=62; 32: single t=126
#define PIDX33(S)                                                          \
    ((S) < 31 ? QMAT + (S)*16 +                                            \
                    (int)((XBIT(4 * (S) + 1) << 3) |                       \
                          (XBIT(4 * (S) + 2) << 2) |                       \
                          (XBIT(4 * (S) + 3) << 1) | XBIT(4 * (S) + 4))    \
              : ((S) == 31 ? 62 * 4 + (int)((XBIT(125) << 1) | XBIT(126))  \
                           : 252 + (int)XBIT(127)))

#define STEP(T, EC, EP, DOPF)                                                 \
    {                                                                         \
        const int p = (T) & 1, np = p ^ 1;                                    \
        const uint4* ewp = (const uint4*)&ewl[p][0] + h * 8;                  \
        uint4 ew_[8];                                                         \
        _Pragma("unroll") for (int q = 0; q < 8; q++) ew_[q] = ewp[q];        \
        __builtin_amdgcn_sched_barrier(0); /* ds_reads issue first */         \
        if (DOPF) { /* prefetch step T+2 (x-selected matrix) */               \
            int pidx_ = PIDX33((T) + 2);                                      \
            const uint4* pf = (const uint4*)(Pb + (size_t)pidx_ * 32768);     \
            _Pragma("unroll") for (int q = 0; q < 8; q++) EP[q] = pf[q * 256];\
            __builtin_amdgcn_sched_barrier(0); /* pin loads here */           \
        }                                                                     \
        unsigned mA = pkmax(pkmax(pkmax4(ew_[0]), pkmax4(ew_[1])),            \
                            pkmax(pkmax4(ew_[2]), pkmax4(ew_[3])));           \
        unsigned mB = pkmax(pkmax(pkmax4(ew_[4]), pkmax4(ew_[5])),            \
                            pkmax(pkmax4(ew_[6]), pkmax4(ew_[7])));           \
        unsigned mm = pkmax(mA, mB);                                          \
        auto mr = __builtin_amdgcn_permlane32_swap(mm, mm, false, false);     \
        mm = pkmax(mr[0], mr[1]);                                             \
        mm = pkmax(mm, mm >> 16);                                             \
        unsigned e16 = (mm >> 10) & 31;                                       \
        float f = __uint_as_float((142u - e16) << 23); /* 2^(15-e16) */       \
        Eacc += (int)e16 - 15;                                                \
        float s0 = 0, s1 = 0, s2 = 0, s3 = 0;                                 \
        float r0 = 0, r1 = 0, r2 = 0, r3 = 0;                                 \
        _Pragma("unroll") for (int q = 0; q < 4; q++) {                       \
            s0 = dot2acc(EC[q].x, ew_[q].x, s0);                              \
            s1 = dot2acc(EC[q].y, ew_[q].y, s1);                              \
            s2 = dot2acc(EC[q].z, ew_[q].z, s2);                              \
            s3 = dot2acc(EC[q].w, ew_[q].w, s3);                              \
        }                                                                     \
        _Pragma("unroll") for (int q = 4; q < 8; q++) {                       \
            r0 = dot2acc(EC[q].x, ew_[q].x, r0);                              \
            r1 = dot2acc(EC[q].y, ew_[q].y, r1);                              \
            r2 = dot2acc(EC[q].z, ew_[q].z, r2);                              \
            r3 = dot2acc(EC[q].w, ew_[q].w, r3);                              \
        }                                                                     \
        float Sh = ((s0 + s1) + (s2 + s3)) + ((r0 + r1) + (r2 + r3));         \
        auto sr = __builtin_amdgcn_permlane32_swap(__float_as_uint(Sh),       \
                                                   __float_as_uint(Sh),       \
                                                   false, false);             \
        float Stot = __uint_as_float(sr[0]) + __uint_as_float(sr[1]);         \
        float pv = Stot * f;                                                  \
        v = pv;                                                               \
        ewl[np][j] = (_Float16)pv;                                            \
        BARRIER();                                                            \
    }

__global__ __launch_bounds__(256, 1) void fwd(const float* __restrict__ x,
                                              const float* __restrict__ lg,
                                              const float* __restrict__ ws,
                                              float* __restrict__ out) {
    __shared__ __align__(16) _Float16 ewl[2][A_];
    __shared__ float sums[4];
    const int b = blockIdx.x, tid = threadIdx.x;
    const int w = tid >> 6, lane = tid & 63;
    const int h = lane >> 5, jl = lane & 31;
    const int j = 32 * w + jl;

    const char* Pb = (const char*)ws + (size_t)h * 2048 + w * 512 + jl * 16;
    const float* LP = ws + LP_OFF;

    // x-bit masks (wave-uniform) for matrix selection
    unsigned long long xlo = __ballot(x[b * D_ + lane] != 0.f);
    unsigned long long xhi = __ballot(x[b * D_ + 64 + lane] != 0.f);

    // init v_0[j] = log_p_a1[j] + bern(x[b][0], j) (log domain, once)
    float ll = lg[j];
    float sp = (ll > 0.f) ? (ll + log1pf(__expf(-ll))) : log1pf(__expf(ll));
    float xv0 = x[b * D_];
    float vlog = LP[j] + ((xv0 != 0.f) ? (ll - sp) : (-sp));
    float mw = wave_max_bcast(vlog);
    sums[w] = mw;
    BARRIER();
    float Phi0 = fmaxf(fmaxf(sums[0], sums[1]), fmaxf(sums[2], sums[3]));
    float v = __expf(vlog - Phi0);
    ewl[0][j] = (_Float16)v;
    int Eacc = 0;

    uint4 E0[8], E1[8], E2[8];
    {   // preload steps 0,1 (E2 filled by step 0's prefetch)
        int i0 = PIDX33(0), i1 = PIDX33(1);
        const uint4* p0 = (const uint4*)(Pb + (size_t)i0 * 32768);
        const uint4* p1 = (const uint4*)(Pb + (size_t)i1 * 32768);
#pragma unroll
        for (int q = 0; q < 8; q++) { E0[q] = p0[q * 256]; E1[q] = p1[q * 256]; }
        __builtin_amdgcn_sched_barrier(0);
    }
    BARRIER();

    for (int t = 0; t < 30; t += 3) {  // steps 0..29
        STEP(t + 0, E0, E2, 1)
        STEP(t + 1, E1, E0, 1)
        STEP(t + 2, E2, E1, 1)
    }
    STEP(30, E0, E2, 1)  // pf 32 -> E2
    STEP(31, E1, E0, 0)
    STEP(32, E2, E1, 0)

    // final: L = Phi0 + ln2*(Eacc - 33 steps * 8 bits of matrix x256 scale)
    //             + log(sum_j v[j])
    float sw = wave_sum_bcast(v) * 0.5f;  // halves duplicate j
    sums[w] = sw;
    BARRIER();
    float tot = (sums[0] + sums[1]) + (sums[2] + sums[3]);
    float L = Phi0 + 0.69314718055994531f * (float)(Eacc - 264) + __logf(tot);
    if (tid < A_) out[b * A_ + tid] = L;
}

extern "C" void kernel_launch(void* const* d_in, const int* in_sizes, int n_in,
                              void* d_out, int out_size, void* d_ws, size_t ws_size,
                              hipStream_t stream) {
    const float* x = (const float*)d_in[0];    // [B,D]
    const float* u1 = (const float*)d_in[1];   // [1,1,1,A]
    const float* uT = (const float*)d_in[2];   // [D-1,A,A]
    const float* lg = (const float*)d_in[3];   // [1,D,1,A]
    float* ws = (float*)d_ws;                  // ~24.6 MB used
    float* out = (float*)d_out;

    pairs<<<dim3(253), dim3(512), 0, stream>>>(uT, u1, x, lg, ws, out);
    quads<<<dim3(496), dim3(512), 0, stream>>>(ws);
    fwd<<<dim3(B_), dim3(256), 0, stream>>>(x, lg, ws, out);
}